// Round 1
// baseline (500.600 us; speedup 1.0000x reference)
//
#include <hip/hip_runtime.h>
#include <hip/hip_bf16.h>
#include <cstdint>

// ---------------- constants ----------------
#define Bn 2
#define Sn 2048
#define Dn 768
#define Hn 12
#define DKn 64
#define DFn 3072
#define Mrows 4096   // B*S

typedef float f32x4 __attribute__((ext_vector_type(4)));
typedef __bf16 bf16x8 __attribute__((ext_vector_type(8)));
typedef short s16x8 __attribute__((ext_vector_type(8)));

__device__ __forceinline__ f32x4 MFMA(s16x8 a, s16x8 b, f32x4 c) {
  return __builtin_amdgcn_mfma_f32_16x16x32_bf16(
      __builtin_bit_cast(bf16x8, a), __builtin_bit_cast(bf16x8, b), c, 0, 0, 0);
}

__device__ __forceinline__ void g2lds16(const void* g, void* l) {
  __builtin_amdgcn_global_load_lds(
      (__attribute__((address_space(1))) void*)(g),
      (__attribute__((address_space(3))) void*)(l), 16, 0, 0);
}

__device__ __forceinline__ short f2bf(float f) {
  unsigned u = __builtin_bit_cast(unsigned, f);
  unsigned r = (u + 0x7fffu + ((u >> 16) & 1u)) >> 16;
  return (short)r;
}

// ---------------- weight transpose: in (R,C) f32 -> out (C,R) bf16 ----------------
__global__ void wtrans(const float* __restrict__ in, short* __restrict__ out, int R, int C) {
  __shared__ float t[32][33];
  int c0 = blockIdx.x * 32, r0 = blockIdx.y * 32;
  int tx = threadIdx.x, ty = threadIdx.y;  // 32 x 8
#pragma unroll
  for (int i = 0; i < 4; i++) t[ty + i * 8][tx] = in[(size_t)(r0 + ty + i * 8) * C + c0 + tx];
  __syncthreads();
#pragma unroll
  for (int i = 0; i < 4; i++) out[(size_t)(c0 + ty + i * 8) * R + r0 + tx] = f2bf(t[tx][ty + i * 8]);
}

// ---------------- layernorm: x f32 (row of 768) -> h bf16 + h f32 ----------------
__global__ __launch_bounds__(256) void ln_kernel(const float* __restrict__ x,
                                                 const float* __restrict__ g,
                                                 const float* __restrict__ b,
                                                 short* __restrict__ hb,
                                                 float* __restrict__ hf) {
  int row = blockIdx.x;
  const float* xr = x + (size_t)row * Dn;
  int tid = threadIdx.x;
  float v[3];
  float s = 0.f, ss = 0.f;
#pragma unroll
  for (int i = 0; i < 3; i++) {
    v[i] = xr[tid + i * 256];
    s += v[i];
    ss += v[i] * v[i];
  }
#pragma unroll
  for (int m = 1; m < 64; m <<= 1) {
    s += __shfl_xor(s, m);
    ss += __shfl_xor(ss, m);
  }
  __shared__ float red[8];
  int w = tid >> 6, lane = tid & 63;
  if (lane == 0) { red[w] = s; red[4 + w] = ss; }
  __syncthreads();
  s = red[0] + red[1] + red[2] + red[3];
  ss = red[4] + red[5] + red[6] + red[7];
  float mean = s * (1.0f / Dn);
  float var = ss * (1.0f / Dn) - mean * mean;
  float rs = rsqrtf(var + 1e-5f);
#pragma unroll
  for (int i = 0; i < 3; i++) {
    int c = tid + i * 256;
    float h = (v[i] - mean) * rs * g[c] + b[c];
    hb[(size_t)row * Dn + c] = f2bf(h);
    hf[(size_t)row * Dn + c] = h;
  }
}

// ---------------- generic 128x128 bf16 GEMM, C = A @ Bt^T ----------------
// EPI 0: C bf16   EPI 1: gelu -> C bf16   EPI 2: Cf = acc + addm (f32)
template <int EPI>
__global__ __launch_bounds__(256) void gemm_bt(const short* __restrict__ A,
                                               const short* __restrict__ Bt,
                                               short* __restrict__ Cb,
                                               const float* __restrict__ addm,
                                               float* __restrict__ Cf,
                                               int M, int N, int K) {
  __shared__ __align__(16) short As[4096];
  __shared__ __align__(16) short Bs[4096];
  int tid = threadIdx.x;
  int lane = tid & 63, w = tid >> 6, g = lane >> 4, lt = lane & 15;
  int wr = w >> 1, wc = w & 1;
  int m0 = blockIdx.x * 128, n0 = blockIdx.y * 128;
  int sr = tid >> 2, su = (tid & 3) * 8;
  const short* Ag = A + (size_t)(m0 + sr) * K + su;
  const short* Bg = Bt + (size_t)(n0 + sr) * K + su;
  f32x4 acc[4][4] = {};
  for (int k0 = 0; k0 < K; k0 += 32) {
    g2lds16(Ag + k0, &As[tid * 8]);
    g2lds16(Ag + k0 + (size_t)64 * K, &As[2048 + tid * 8]);
    g2lds16(Bg + k0, &Bs[tid * 8]);
    g2lds16(Bg + k0 + (size_t)64 * K, &Bs[2048 + tid * 8]);
    __syncthreads();
    s16x8 af[4], bfr[4];
#pragma unroll
    for (int i = 0; i < 4; i++) {
      af[i] = *(const s16x8*)&As[(wr * 64 + i * 16 + lt) * 32 + g * 8];
      bfr[i] = *(const s16x8*)&Bs[(wc * 64 + i * 16 + lt) * 32 + g * 8];
    }
#pragma unroll
    for (int mi = 0; mi < 4; mi++)
#pragma unroll
      for (int ni = 0; ni < 4; ni++) acc[mi][ni] = MFMA(af[mi], bfr[ni], acc[mi][ni]);
    __syncthreads();
  }
#pragma unroll
  for (int mi = 0; mi < 4; mi++) {
    int m = m0 + wr * 64 + mi * 16 + g * 4;
#pragma unroll
    for (int ni = 0; ni < 4; ni++) {
      int n = n0 + wc * 64 + ni * 16 + lt;
#pragma unroll
      for (int r = 0; r < 4; r++) {
        float v = acc[mi][ni][r];
        size_t idx = (size_t)(m + r) * N + n;
        if constexpr (EPI == 0) {
          Cb[idx] = f2bf(v);
        } else if constexpr (EPI == 1) {
          float ge = 0.5f * v * (1.0f + erff(v * 0.70710678f));
          Cb[idx] = f2bf(ge);
        } else {
          Cf[idx] = v + addm[idx];
        }
      }
    }
  }
}

// ---------------- V transpose: qkv v-cols -> vt (B,H,DK,S) bf16 ----------------
__global__ void vtrans(const short* __restrict__ qkv, short* __restrict__ vt) {
  __shared__ short t[32][33];
  int bh = blockIdx.z;
  int b = bh / Hn, h = bh % Hn;
  int s0 = blockIdx.x * 32, d0 = blockIdx.y * 32;
  int tx = threadIdx.x, ty = threadIdx.y;
#pragma unroll
  for (int i = 0; i < 4; i++)
    t[ty + i * 8][tx] =
        qkv[(size_t)(b * Sn + s0 + ty + i * 8) * (3 * Dn) + 2 * Dn + h * DKn + d0 + tx];
  __syncthreads();
#pragma unroll
  for (int i = 0; i < 4; i++)
    vt[(size_t)(bh * DKn + d0 + ty + i * 8) * Sn + s0 + tx] = t[tx][ty + i * 8];
}

// ---------------- fused attention (causal, bias, softcap 30, static-max softmax) ----
__global__ __launch_bounds__(256) void attn_kernel(const short* __restrict__ qkv,
                                                   const short* __restrict__ vt,
                                                   const float* __restrict__ bias,
                                                   short* __restrict__ o) {
  __shared__ __align__(16) short plds[4][16][40];
  int qt = blockIdx.x, bh = blockIdx.y;
  int b = bh / Hn, h = bh % Hn;
  int tid = threadIdx.x, w = tid >> 6, lane = tid & 63, g = lane >> 4, lt = lane & 15;
  int q0 = qt * 64 + w * 16;
  const short* qbase = qkv + (size_t)(b * Sn + q0 + lt) * (3 * Dn) + h * DKn;
  s16x8 qf0 = *(const s16x8*)(qbase + g * 8);
  s16x8 qf1 = *(const s16x8*)(qbase + 32 + g * 8);
  f32x4 oacc[4] = {};
  float lsum[4] = {0.f, 0.f, 0.f, 0.f};
  int ktmax = qt * 2 + 2;
  const float* biasrow = bias + ((size_t)b * Sn + q0 + g * 4) * Sn;
  for (int kt = 0; kt < ktmax; kt++) {
    int kc0 = kt * 32;
    const short* kbase = qkv + (size_t)(b * Sn + kc0 + lt) * (3 * Dn) + Dn + h * DKn;
    s16x8 kf00 = *(const s16x8*)(kbase + g * 8);
    s16x8 kf01 = *(const s16x8*)(kbase + 32 + g * 8);
    s16x8 kf10 = *(const s16x8*)(kbase + (size_t)16 * (3 * Dn) + g * 8);
    s16x8 kf11 = *(const s16x8*)(kbase + (size_t)16 * (3 * Dn) + 32 + g * 8);
    f32x4 s0 = {}, s1 = {};
    s0 = MFMA(qf0, kf00, s0);
    s0 = MFMA(qf1, kf01, s0);
    s1 = MFMA(qf0, kf10, s1);
    s1 = MFMA(qf1, kf11, s1);
#pragma unroll
    for (int r = 0; r < 4; r++) {
      int qrow = q0 + g * 4 + r;
      {
        int kc = kc0 + lt;
        float sc = s0[r] * 0.125f + biasrow[(size_t)r * Sn + kc];
        float e = __expf(sc * (1.0f / 15.0f));
        float p = __expf(-60.0f / (1.0f + e));
        p = (kc <= qrow) ? p : 0.0f;
        lsum[r] += p;
        plds[w][g * 4 + r][lt] = f2bf(p);
      }
      {
        int kc = kc0 + 16 + lt;
        float sc = s1[r] * 0.125f + biasrow[(size_t)r * Sn + kc];
        float e = __expf(sc * (1.0f / 15.0f));
        float p = __expf(-60.0f / (1.0f + e));
        p = (kc <= qrow) ? p : 0.0f;
        lsum[r] += p;
        plds[w][g * 4 + r][16 + lt] = f2bf(p);
      }
    }
    s16x8 pf = *(const s16x8*)&plds[w][lt][g * 8];
    const short* vbase = vt + ((size_t)(bh * DKn) + lt) * Sn + kc0 + g * 8;
#pragma unroll
    for (int dt = 0; dt < 4; dt++) {
      s16x8 vf = *(const s16x8*)(vbase + (size_t)dt * 16 * Sn);
      oacc[dt] = MFMA(pf, vf, oacc[dt]);
    }
  }
#pragma unroll
  for (int r = 0; r < 4; r++) {
    float l = lsum[r];
    l += __shfl_xor(l, 1);
    l += __shfl_xor(l, 2);
    l += __shfl_xor(l, 4);
    l += __shfl_xor(l, 8);
    lsum[r] = 1.0f / l;
  }
  short* obase = o + (size_t)(b * Sn + q0 + g * 4) * Dn + h * DKn + lt;
#pragma unroll
  for (int dt = 0; dt < 4; dt++)
#pragma unroll
    for (int r = 0; r < 4; r++) obase[(size_t)r * Dn + dt * 16] = f2bf(oacc[dt][r] * lsum[r]);
}

// ---------------- launch ----------------
extern "C" void kernel_launch(void* const* d_in, const int* in_sizes, int n_in,
                              void* d_out, int out_size, void* d_ws, size_t ws_size,
                              hipStream_t stream) {
  const float* x = (const float*)d_in[0];
  const float* bias = (const float*)d_in[1];
  // d_in[2] = attn_mask (exact causal tril) -> applied analytically
  const float* Wq = (const float*)d_in[3];
  const float* Wk = (const float*)d_in[4];
  const float* Wv = (const float*)d_in[5];
  const float* Wo = (const float*)d_in[6];
  const float* W1 = (const float*)d_in[7];
  const float* W2 = (const float*)d_in[8];
  const float* g1 = (const float*)d_in[9];
  const float* b1 = (const float*)d_in[10];
  const float* g2 = (const float*)d_in[11];
  const float* b2 = (const float*)d_in[12];
  float* out = (float*)d_out;
  char* ws = (char*)d_ws;

  short* wqkv_t = (short*)(ws + 0);          // 2304x768 bf16
  short* wo_t = (short*)(ws + 3538944);      // 768x768
  short* w1_t = (short*)(ws + 4718592);      // 3072x768
  short* w2_t = (short*)(ws + 9437184);      // 768x3072
  short* hb = (short*)(ws + 14155776);       // 4096x768 bf16 (reused as h2b)
  float* hf = (float*)(ws + 20447232);       // 4096x768 f32  (reused as h2f)
  short* qkv = (short*)(ws + 33030144);      // 4096x2304 bf16 (region reused by a1 4096x3072)
  short* a1 = qkv;
  short* vt = (short*)(ws + 58195968);       // 24x64x2048 bf16 (region reused by x1 f32)
  float* x1 = (float*)(ws + 58195968);
  short* o_ = (short*)(ws + 70778880);       // 4096x768 bf16
  short* h2b = hb;
  float* h2f = hf;

  dim3 tb(32, 8);
  wtrans<<<dim3(24, 24), tb, 0, stream>>>(Wq, wqkv_t, Dn, Dn);
  wtrans<<<dim3(24, 24), tb, 0, stream>>>(Wk, wqkv_t + (size_t)Dn * Dn, Dn, Dn);
  wtrans<<<dim3(24, 24), tb, 0, stream>>>(Wv, wqkv_t + (size_t)2 * Dn * Dn, Dn, Dn);
  wtrans<<<dim3(24, 24), tb, 0, stream>>>(Wo, wo_t, Dn, Dn);
  wtrans<<<dim3(96, 24), tb, 0, stream>>>(W1, w1_t, Dn, DFn);
  wtrans<<<dim3(24, 96), tb, 0, stream>>>(W2, w2_t, DFn, Dn);

  ln_kernel<<<Mrows, 256, 0, stream>>>(x, g1, b1, hb, hf);

  gemm_bt<0><<<dim3(32, 18), 256, 0, stream>>>(hb, wqkv_t, qkv, nullptr, nullptr,
                                               Mrows, 3 * Dn, Dn);
  vtrans<<<dim3(64, 2, Bn * Hn), tb, 0, stream>>>(qkv, vt);
  attn_kernel<<<dim3(32, Bn * Hn), 256, 0, stream>>>(qkv, vt, bias, o_);

  gemm_bt<2><<<dim3(32, 6), 256, 0, stream>>>(o_, wo_t, nullptr, hf, x1,
                                              Mrows, Dn, Dn);
  ln_kernel<<<Mrows, 256, 0, stream>>>(x1, g2, b2, h2b, h2f);
  gemm_bt<1><<<dim3(32, 24), 256, 0, stream>>>(h2b, w1_t, a1, nullptr, nullptr,
                                               Mrows, DFn, Dn);
  gemm_bt<2><<<dim3(32, 6), 256, 0, stream>>>(a1, w2_t, nullptr, h2f, out,
                                              Mrows, Dn, DFn);
}

// Round 2
// 454.872 us; speedup vs baseline: 1.1005x; 1.1005x over previous
//
#include <hip/hip_runtime.h>
#include <hip/hip_bf16.h>
#include <cstdint>

// ---------------- constants ----------------
#define Bn 2
#define Sn 2048
#define Dn 768
#define Hn 12
#define DKn 64
#define DFn 3072
#define Mrows 4096   // B*S

typedef float f32x4 __attribute__((ext_vector_type(4)));
typedef __bf16 bf16x8 __attribute__((ext_vector_type(8)));
typedef short s16x8 __attribute__((ext_vector_type(8)));
typedef short s16x4 __attribute__((ext_vector_type(4)));

__device__ __forceinline__ f32x4 MFMA(s16x8 a, s16x8 b, f32x4 c) {
  return __builtin_amdgcn_mfma_f32_16x16x32_bf16(
      __builtin_bit_cast(bf16x8, a), __builtin_bit_cast(bf16x8, b), c, 0, 0, 0);
}

__device__ __forceinline__ void g2lds16(const void* g, void* l) {
  __builtin_amdgcn_global_load_lds(
      (__attribute__((address_space(1))) void*)(g),
      (__attribute__((address_space(3))) void*)(l), 16, 0, 0);
}

__device__ __forceinline__ short f2bf(float f) {
  unsigned u = __builtin_bit_cast(unsigned, f);
  unsigned r = (u + 0x7fffu + ((u >> 16) & 1u)) >> 16;
  return (short)r;
}

// ---------------- weight transpose: in (R,C) f32 -> out (C,R) bf16 ----------------
__global__ void wtrans(const float* __restrict__ in, short* __restrict__ out, int R, int C) {
  __shared__ float t[32][33];
  int c0 = blockIdx.x * 32, r0 = blockIdx.y * 32;
  int tx = threadIdx.x, ty = threadIdx.y;  // 32 x 8
#pragma unroll
  for (int i = 0; i < 4; i++) t[ty + i * 8][tx] = in[(size_t)(r0 + ty + i * 8) * C + c0 + tx];
  __syncthreads();
#pragma unroll
  for (int i = 0; i < 4; i++) out[(size_t)(c0 + ty + i * 8) * R + r0 + tx] = f2bf(t[tx][ty + i * 8]);
}

// ---------------- layernorm: x f32 (row of 768) -> h bf16 + h f32 ----------------
__global__ __launch_bounds__(256) void ln_kernel(const float* __restrict__ x,
                                                 const float* __restrict__ g,
                                                 const float* __restrict__ b,
                                                 short* __restrict__ hb,
                                                 float* __restrict__ hf) {
  int row = blockIdx.x;
  const float* xr = x + (size_t)row * Dn;
  int tid = threadIdx.x;
  float v[3];
  float s = 0.f, ss = 0.f;
#pragma unroll
  for (int i = 0; i < 3; i++) {
    v[i] = xr[tid + i * 256];
    s += v[i];
    ss += v[i] * v[i];
  }
#pragma unroll
  for (int m = 1; m < 64; m <<= 1) {
    s += __shfl_xor(s, m);
    ss += __shfl_xor(ss, m);
  }
  __shared__ float red[8];
  int w = tid >> 6, lane = tid & 63;
  if (lane == 0) { red[w] = s; red[4 + w] = ss; }
  __syncthreads();
  s = red[0] + red[1] + red[2] + red[3];
  ss = red[4] + red[5] + red[6] + red[7];
  float mean = s * (1.0f / Dn);
  float var = ss * (1.0f / Dn) - mean * mean;
  float rs = rsqrtf(var + 1e-5f);
#pragma unroll
  for (int i = 0; i < 3; i++) {
    int c = tid + i * 256;
    float h = (v[i] - mean) * rs * g[c] + b[c];
    hb[(size_t)row * Dn + c] = f2bf(h);
    hf[(size_t)row * Dn + c] = h;
  }
}

// ---------------- generic 128x128 bf16 GEMM, C = A @ Bt^T ----------------
// EPI 0: C bf16   EPI 1: gelu -> C bf16   EPI 2: Cf = acc + addm (f32)
template <int EPI>
__global__ __launch_bounds__(256) void gemm_bt(const short* __restrict__ A,
                                               const short* __restrict__ Bt,
                                               short* __restrict__ Cb,
                                               const float* __restrict__ addm,
                                               float* __restrict__ Cf,
                                               int M, int N, int K) {
  __shared__ __align__(16) short As[4096];
  __shared__ __align__(16) short Bs[4096];
  int tid = threadIdx.x;
  int lane = tid & 63, w = tid >> 6, g = lane >> 4, lt = lane & 15;
  int wr = w >> 1, wc = w & 1;
  int m0 = blockIdx.x * 128, n0 = blockIdx.y * 128;
  int sr = tid >> 2, su = (tid & 3) * 8;
  const short* Ag = A + (size_t)(m0 + sr) * K + su;
  const short* Bg = Bt + (size_t)(n0 + sr) * K + su;
  f32x4 acc[4][4] = {};
  for (int k0 = 0; k0 < K; k0 += 32) {
    g2lds16(Ag + k0, &As[tid * 8]);
    g2lds16(Ag + k0 + (size_t)64 * K, &As[2048 + tid * 8]);
    g2lds16(Bg + k0, &Bs[tid * 8]);
    g2lds16(Bg + k0 + (size_t)64 * K, &Bs[2048 + tid * 8]);
    __syncthreads();
    s16x8 af[4], bfr[4];
#pragma unroll
    for (int i = 0; i < 4; i++) {
      af[i] = *(const s16x8*)&As[(wr * 64 + i * 16 + lt) * 32 + g * 8];
      bfr[i] = *(const s16x8*)&Bs[(wc * 64 + i * 16 + lt) * 32 + g * 8];
    }
#pragma unroll
    for (int mi = 0; mi < 4; mi++)
#pragma unroll
      for (int ni = 0; ni < 4; ni++) acc[mi][ni] = MFMA(af[mi], bfr[ni], acc[mi][ni]);
    __syncthreads();
  }
#pragma unroll
  for (int mi = 0; mi < 4; mi++) {
    int m = m0 + wr * 64 + mi * 16 + g * 4;
#pragma unroll
    for (int ni = 0; ni < 4; ni++) {
      int n = n0 + wc * 64 + ni * 16 + lt;
#pragma unroll
      for (int r = 0; r < 4; r++) {
        float v = acc[mi][ni][r];
        size_t idx = (size_t)(m + r) * N + n;
        if constexpr (EPI == 0) {
          Cb[idx] = f2bf(v);
        } else if constexpr (EPI == 1) {
          float ge = 0.5f * v * (1.0f + erff(v * 0.70710678f));
          Cb[idx] = f2bf(ge);
        } else {
          Cf[idx] = v + addm[idx];
        }
      }
    }
  }
}

// ---------------- V transpose: qkv v-cols -> vt (B,H,DK,S) bf16 ----------------
__global__ void vtrans(const short* __restrict__ qkv, short* __restrict__ vt) {
  __shared__ short t[32][33];
  int bh = blockIdx.z;
  int b = bh / Hn, h = bh % Hn;
  int s0 = blockIdx.x * 32, d0 = blockIdx.y * 32;
  int tx = threadIdx.x, ty = threadIdx.y;
#pragma unroll
  for (int i = 0; i < 4; i++)
    t[ty + i * 8][tx] =
        qkv[(size_t)(b * Sn + s0 + ty + i * 8) * (3 * Dn) + 2 * Dn + h * DKn + d0 + tx];
  __syncthreads();
#pragma unroll
  for (int i = 0; i < 4; i++)
    vt[(size_t)(bh * DKn + d0 + ty + i * 8) * Sn + s0 + tx] = t[tx][ty + i * 8];
}

// ---------------- fused attention, wave-split-K flash-decoding style --------------
// block = 16 q-rows (one (b,h,qt)); 4 waves split the causal k-range in 64-col tiles.
// static-max softmax (softcap => scores <= 30): p = exp(sc - 30), no rescaling, so
// partial O / partial row-sums across waves combine by simple addition.
__global__ __launch_bounds__(256) void attn_kernel(const short* __restrict__ qkv,
                                                   const short* __restrict__ vt,
                                                   const float* __restrict__ bias,
                                                   short* __restrict__ o) {
  __shared__ __align__(16) short plds[4][16][72];
  __shared__ __align__(16) float obuf[4][16][68];
  __shared__ float lsumbuf[4][16];
  int qt = 127 - blockIdx.x;  // longest-first dispatch
  int bh = blockIdx.y;
  int b = bh / Hn, h = bh - b * Hn;
  int tid = threadIdx.x, w = tid >> 6, lane = tid & 63, g = lane >> 4, lt = lane & 15;
  int q0 = qt * 16;
  const short* qbase = qkv + (size_t)(b * Sn + q0 + lt) * (3 * Dn) + h * DKn;
  s16x8 qf0 = *(const s16x8*)(qbase + g * 8);
  s16x8 qf1 = *(const s16x8*)(qbase + 32 + g * 8);
  f32x4 oacc[4] = {};
  float lsum[4] = {0.f, 0.f, 0.f, 0.f};
  int n64 = (q0 + 16 + 63) >> 6;  // number of 64-col k-tiles in causal range
  const float* biasrow = bias + ((size_t)b * Sn + q0 + g * 4) * Sn;
  for (int j = w; j < n64; j += 4) {
    int kc0 = j << 6;
    const short* kbase = qkv + (size_t)(b * Sn + kc0 + lt) * (3 * Dn) + Dn + h * DKn;
    s16x8 kf[4][2];
#pragma unroll
    for (int c = 0; c < 4; c++) {
      kf[c][0] = *(const s16x8*)(kbase + (size_t)c * 16 * (3 * Dn) + g * 8);
      kf[c][1] = *(const s16x8*)(kbase + (size_t)c * 16 * (3 * Dn) + 32 + g * 8);
    }
    const short* vbase = vt + ((size_t)bh * DKn + lt) * Sn + kc0 + g * 8;
    s16x8 vf[4][2];
#pragma unroll
    for (int dt = 0; dt < 4; dt++) {
      vf[dt][0] = *(const s16x8*)(vbase + (size_t)dt * 16 * Sn);
      vf[dt][1] = *(const s16x8*)(vbase + (size_t)dt * 16 * Sn + 32);
    }
    f32x4 s[4] = {};
#pragma unroll
    for (int c = 0; c < 4; c++) {
      s[c] = MFMA(qf0, kf[c][0], s[c]);
      s[c] = MFMA(qf1, kf[c][1], s[c]);
    }
    bool needmask = (kc0 + 63 > q0);
#pragma unroll
    for (int c = 0; c < 4; c++) {
#pragma unroll
      for (int r = 0; r < 4; r++) {
        int kc = kc0 + c * 16 + lt;
        float sc = s[c][r] * 0.125f + biasrow[(size_t)r * Sn + kc];
        float e = __expf(sc * (1.0f / 15.0f));
        float p = __expf(-60.0f * __builtin_amdgcn_rcpf(1.0f + e));
        if (needmask) p = (kc <= q0 + g * 4 + r) ? p : 0.0f;
        lsum[r] += p;
        plds[w][g * 4 + r][c * 16 + lt] = f2bf(p);
      }
    }
    s16x8 pf0 = *(const s16x8*)&plds[w][lt][g * 8];
    s16x8 pf1 = *(const s16x8*)&plds[w][lt][32 + g * 8];
#pragma unroll
    for (int dt = 0; dt < 4; dt++) {
      oacc[dt] = MFMA(pf0, vf[dt][0], oacc[dt]);
      oacc[dt] = MFMA(pf1, vf[dt][1], oacc[dt]);
    }
  }
  // per-wave row sums (reduce across the 16 lanes of each row group)
#pragma unroll
  for (int r = 0; r < 4; r++) {
    float l = lsum[r];
    l += __shfl_xor(l, 1);
    l += __shfl_xor(l, 2);
    l += __shfl_xor(l, 4);
    l += __shfl_xor(l, 8);
    lsum[r] = l;
  }
#pragma unroll
  for (int dt = 0; dt < 4; dt++)
#pragma unroll
    for (int r = 0; r < 4; r++) obuf[w][g * 4 + r][dt * 16 + lt] = oacc[dt][r];
  if (lt == 0) {
#pragma unroll
    for (int r = 0; r < 4; r++) lsumbuf[w][g * 4 + r] = lsum[r];
  }
  __syncthreads();
  // combine: thread t handles q-row (t>>4), 4 dk cols
  int q = tid >> 4, dk0 = (tid & 15) * 4;
  f32x4 a0 = *(const f32x4*)&obuf[0][q][dk0];
  f32x4 a1 = *(const f32x4*)&obuf[1][q][dk0];
  f32x4 a2 = *(const f32x4*)&obuf[2][q][dk0];
  f32x4 a3 = *(const f32x4*)&obuf[3][q][dk0];
  float l = lsumbuf[0][q] + lsumbuf[1][q] + lsumbuf[2][q] + lsumbuf[3][q];
  float inv = __builtin_amdgcn_rcpf(l);
  f32x4 acc = (a0 + a1) + (a2 + a3);
  s16x4 outv;
  outv[0] = f2bf(acc[0] * inv);
  outv[1] = f2bf(acc[1] * inv);
  outv[2] = f2bf(acc[2] * inv);
  outv[3] = f2bf(acc[3] * inv);
  *(s16x4*)&o[(size_t)(b * Sn + q0 + q) * Dn + h * DKn + dk0] = outv;
}

// ---------------- launch ----------------
extern "C" void kernel_launch(void* const* d_in, const int* in_sizes, int n_in,
                              void* d_out, int out_size, void* d_ws, size_t ws_size,
                              hipStream_t stream) {
  const float* x = (const float*)d_in[0];
  const float* bias = (const float*)d_in[1];
  // d_in[2] = attn_mask (exact causal tril) -> applied analytically
  const float* Wq = (const float*)d_in[3];
  const float* Wk = (const float*)d_in[4];
  const float* Wv = (const float*)d_in[5];
  const float* Wo = (const float*)d_in[6];
  const float* W1 = (const float*)d_in[7];
  const float* W2 = (const float*)d_in[8];
  const float* g1 = (const float*)d_in[9];
  const float* b1 = (const float*)d_in[10];
  const float* g2 = (const float*)d_in[11];
  const float* b2 = (const float*)d_in[12];
  float* out = (float*)d_out;
  char* ws = (char*)d_ws;

  short* wqkv_t = (short*)(ws + 0);          // 2304x768 bf16
  short* wo_t = (short*)(ws + 3538944);      // 768x768
  short* w1_t = (short*)(ws + 4718592);      // 3072x768
  short* w2_t = (short*)(ws + 9437184);      // 768x3072
  short* hb = (short*)(ws + 14155776);       // 4096x768 bf16 (reused as h2b)
  float* hf = (float*)(ws + 20447232);       // 4096x768 f32  (reused as h2f)
  short* qkv = (short*)(ws + 33030144);      // 4096x2304 bf16 (region reused by a1 4096x3072)
  short* a1 = qkv;
  short* vt = (short*)(ws + 58195968);       // 24x64x2048 bf16 (region reused by x1 f32)
  float* x1 = (float*)(ws + 58195968);
  short* o_ = (short*)(ws + 70778880);       // 4096x768 bf16
  short* h2b = hb;
  float* h2f = hf;

  dim3 tb(32, 8);
  wtrans<<<dim3(24, 24), tb, 0, stream>>>(Wq, wqkv_t, Dn, Dn);
  wtrans<<<dim3(24, 24), tb, 0, stream>>>(Wk, wqkv_t + (size_t)Dn * Dn, Dn, Dn);
  wtrans<<<dim3(24, 24), tb, 0, stream>>>(Wv, wqkv_t + (size_t)2 * Dn * Dn, Dn, Dn);
  wtrans<<<dim3(24, 24), tb, 0, stream>>>(Wo, wo_t, Dn, Dn);
  wtrans<<<dim3(96, 24), tb, 0, stream>>>(W1, w1_t, Dn, DFn);
  wtrans<<<dim3(24, 96), tb, 0, stream>>>(W2, w2_t, DFn, Dn);

  ln_kernel<<<Mrows, 256, 0, stream>>>(x, g1, b1, hb, hf);

  gemm_bt<0><<<dim3(32, 18), 256, 0, stream>>>(hb, wqkv_t, qkv, nullptr, nullptr,
                                               Mrows, 3 * Dn, Dn);
  vtrans<<<dim3(64, 2, Bn * Hn), tb, 0, stream>>>(qkv, vt);
  attn_kernel<<<dim3(128, Bn * Hn), 256, 0, stream>>>(qkv, vt, bias, o_);

  gemm_bt<2><<<dim3(32, 6), 256, 0, stream>>>(o_, wo_t, nullptr, hf, x1,
                                              Mrows, Dn, Dn);
  ln_kernel<<<Mrows, 256, 0, stream>>>(x1, g2, b2, h2b, h2f);
  gemm_bt<1><<<dim3(32, 24), 256, 0, stream>>>(h2b, w1_t, a1, nullptr, nullptr,
                                               Mrows, DFn, Dn);
  gemm_bt<2><<<dim3(32, 6), 256, 0, stream>>>(a1, w2_t, nullptr, h2f, out,
                                              Mrows, Dn, DFn);
}

// Round 3
// 418.850 us; speedup vs baseline: 1.1952x; 1.0860x over previous
//
#include <hip/hip_runtime.h>
#include <hip/hip_bf16.h>
#include <cstdint>

// ---------------- constants ----------------
#define Bn 2
#define Sn 2048
#define Dn 768
#define Hn 12
#define DKn 64
#define DFn 3072
#define Mrows 4096   // B*S

typedef float f32x4 __attribute__((ext_vector_type(4)));
typedef __bf16 bf16x8 __attribute__((ext_vector_type(8)));
typedef short s16x8 __attribute__((ext_vector_type(8)));
typedef short s16x4 __attribute__((ext_vector_type(4)));

__device__ __forceinline__ f32x4 MFMA(s16x8 a, s16x8 b, f32x4 c) {
  return __builtin_amdgcn_mfma_f32_16x16x32_bf16(
      __builtin_bit_cast(bf16x8, a), __builtin_bit_cast(bf16x8, b), c, 0, 0, 0);
}

__device__ __forceinline__ void g2lds16(const void* g, void* l) {
  __builtin_amdgcn_global_load_lds(
      (__attribute__((address_space(1))) void*)(g),
      (__attribute__((address_space(3))) void*)(l), 16, 0, 0);
}

__device__ __forceinline__ short f2bf(float f) {
  unsigned u = __builtin_bit_cast(unsigned, f);
  unsigned r = (u + 0x7fffu + ((u >> 16) & 1u)) >> 16;
  return (short)r;
}

// ---------------- weight transpose: in (R,C) f32 -> out (C,R) bf16 ----------------
__global__ void wtrans(const float* __restrict__ in, short* __restrict__ out, int R, int C) {
  __shared__ float t[32][33];
  int c0 = blockIdx.x * 32, r0 = blockIdx.y * 32;
  int tx = threadIdx.x, ty = threadIdx.y;  // 32 x 8
#pragma unroll
  for (int i = 0; i < 4; i++) t[ty + i * 8][tx] = in[(size_t)(r0 + ty + i * 8) * C + c0 + tx];
  __syncthreads();
#pragma unroll
  for (int i = 0; i < 4; i++) out[(size_t)(c0 + ty + i * 8) * R + r0 + tx] = f2bf(t[tx][ty + i * 8]);
}

// ---------------- layernorm: x f32 (row of 768) -> h bf16 + h f32 ----------------
__global__ __launch_bounds__(256) void ln_kernel(const float* __restrict__ x,
                                                 const float* __restrict__ g,
                                                 const float* __restrict__ b,
                                                 short* __restrict__ hb,
                                                 float* __restrict__ hf) {
  int row = blockIdx.x;
  const float* xr = x + (size_t)row * Dn;
  int tid = threadIdx.x;
  float v[3];
  float s = 0.f, ss = 0.f;
#pragma unroll
  for (int i = 0; i < 3; i++) {
    v[i] = xr[tid + i * 256];
    s += v[i];
    ss += v[i] * v[i];
  }
#pragma unroll
  for (int m = 1; m < 64; m <<= 1) {
    s += __shfl_xor(s, m);
    ss += __shfl_xor(ss, m);
  }
  __shared__ float red[8];
  int w = tid >> 6, lane = tid & 63;
  if (lane == 0) { red[w] = s; red[4 + w] = ss; }
  __syncthreads();
  s = red[0] + red[1] + red[2] + red[3];
  ss = red[4] + red[5] + red[6] + red[7];
  float mean = s * (1.0f / Dn);
  float var = ss * (1.0f / Dn) - mean * mean;
  float rs = rsqrtf(var + 1e-5f);
#pragma unroll
  for (int i = 0; i < 3; i++) {
    int c = tid + i * 256;
    float h = (v[i] - mean) * rs * g[c] + b[c];
    hb[(size_t)row * Dn + c] = f2bf(h);
    hf[(size_t)row * Dn + c] = h;
  }
}

// ---------------- generic 128x128 bf16 GEMM, C = A @ Bt^T ----------------
// EPI 0: C bf16   EPI 1: gelu -> C bf16   EPI 2: Cf = acc + addm (f32)
template <int EPI>
__global__ __launch_bounds__(256) void gemm_bt(const short* __restrict__ A,
                                               const short* __restrict__ Bt,
                                               short* __restrict__ Cb,
                                               const float* __restrict__ addm,
                                               float* __restrict__ Cf,
                                               int M, int N, int K) {
  __shared__ __align__(16) short As[4096];
  __shared__ __align__(16) short Bs[4096];
  int tid = threadIdx.x;
  int lane = tid & 63, w = tid >> 6, g = lane >> 4, lt = lane & 15;
  int wr = w >> 1, wc = w & 1;
  int m0 = blockIdx.x * 128, n0 = blockIdx.y * 128;
  int sr = tid >> 2, su = (tid & 3) * 8;
  const short* Ag = A + (size_t)(m0 + sr) * K + su;
  const short* Bg = Bt + (size_t)(n0 + sr) * K + su;
  f32x4 acc[4][4] = {};
  for (int k0 = 0; k0 < K; k0 += 32) {
    g2lds16(Ag + k0, &As[tid * 8]);
    g2lds16(Ag + k0 + (size_t)64 * K, &As[2048 + tid * 8]);
    g2lds16(Bg + k0, &Bs[tid * 8]);
    g2lds16(Bg + k0 + (size_t)64 * K, &Bs[2048 + tid * 8]);
    __syncthreads();
    s16x8 af[4], bfr[4];
#pragma unroll
    for (int i = 0; i < 4; i++) {
      af[i] = *(const s16x8*)&As[(wr * 64 + i * 16 + lt) * 32 + g * 8];
      bfr[i] = *(const s16x8*)&Bs[(wc * 64 + i * 16 + lt) * 32 + g * 8];
    }
#pragma unroll
    for (int mi = 0; mi < 4; mi++)
#pragma unroll
      for (int ni = 0; ni < 4; ni++) acc[mi][ni] = MFMA(af[mi], bfr[ni], acc[mi][ni]);
    __syncthreads();
  }
#pragma unroll
  for (int mi = 0; mi < 4; mi++) {
    int m = m0 + wr * 64 + mi * 16 + g * 4;
#pragma unroll
    for (int ni = 0; ni < 4; ni++) {
      int n = n0 + wc * 64 + ni * 16 + lt;
#pragma unroll
      for (int r = 0; r < 4; r++) {
        float v = acc[mi][ni][r];
        size_t idx = (size_t)(m + r) * N + n;
        if constexpr (EPI == 0) {
          Cb[idx] = f2bf(v);
        } else if constexpr (EPI == 1) {
          float ge = 0.5f * v * (1.0f + erff(v * 0.70710678f));
          Cb[idx] = f2bf(ge);
        } else {
          Cf[idx] = v + addm[idx];
        }
      }
    }
  }
}

// ---------------- V transpose: qkv v-cols -> vt (B,H,DK,S) bf16 ----------------
__global__ void vtrans(const short* __restrict__ qkv, short* __restrict__ vt) {
  __shared__ short t[32][33];
  int bh = blockIdx.z;
  int b = bh / Hn, h = bh % Hn;
  int s0 = blockIdx.x * 32, d0 = blockIdx.y * 32;
  int tx = threadIdx.x, ty = threadIdx.y;
#pragma unroll
  for (int i = 0; i < 4; i++)
    t[ty + i * 8][tx] =
        qkv[(size_t)(b * Sn + s0 + ty + i * 8) * (3 * Dn) + 2 * Dn + h * DKn + d0 + tx];
  __syncthreads();
#pragma unroll
  for (int i = 0; i < 4; i++)
    vt[(size_t)(bh * DKn + d0 + ty + i * 8) * Sn + s0 + tx] = t[tx][ty + i * 8];
}

// ---------------- fused attention, wave-split-K flash-decoding style --------------
// block = 16 q-rows (one (b,h,qt)); 4 waves split the causal k-range in 64-col tiles.
// static-max softmax (softcap => scores <= 30): p = exp(sc - 30), no rescaling, so
// partial O / partial row-sums across waves combine by simple addition.
// All global loads for an iteration are batch-issued (K, then bias, then V) so each
// iteration exposes ~one memory latency instead of ~16 serial ones.
__global__ __launch_bounds__(256) void attn_kernel(const short* __restrict__ qkv,
                                                   const short* __restrict__ vt,
                                                   const float* __restrict__ bias,
                                                   short* __restrict__ o) {
  __shared__ __align__(16) short plds[4][16][72];
  __shared__ __align__(16) float obuf[4][16][68];
  __shared__ float lsumbuf[4][16];
  int bh = blockIdx.x;              // heads adjacent -> bias rows reused in L2/L3
  int qt = 127 - (int)blockIdx.y;   // longest-first dispatch
  int b = bh / Hn, h = bh - b * Hn;
  int tid = threadIdx.x, w = tid >> 6, lane = tid & 63, g = lane >> 4, lt = lane & 15;
  int q0 = qt * 16;
  const short* qbase = qkv + (size_t)(b * Sn + q0 + lt) * (3 * Dn) + h * DKn;
  s16x8 qf0 = *(const s16x8*)(qbase + g * 8);
  s16x8 qf1 = *(const s16x8*)(qbase + 32 + g * 8);
  f32x4 oacc[4] = {};
  float lsum[4] = {0.f, 0.f, 0.f, 0.f};
  int n64 = (q0 + 16 + 63) >> 6;  // number of 64-col k-tiles in causal range
  const float* biasrow = bias + ((size_t)b * Sn + q0 + g * 4) * Sn;
  const float C1 = 0.0120224586f;   // 0.125/15*log2(e)
  const float C2 = 0.0961796722f;   // (1/15)*log2(e)
  const float C3 = -86.5617013f;    // -60*log2(e)
  for (int j = w; j < n64; j += 4) {
    int kc0 = j << 6;
    // ---- K fragment loads (batch-issued) ----
    const short* kbase = qkv + (size_t)(b * Sn + kc0 + lt) * (3 * Dn) + Dn + h * DKn;
    s16x8 kf[4][2];
#pragma unroll
    for (int c = 0; c < 4; c++) {
      kf[c][0] = *(const s16x8*)(kbase + (size_t)c * 16 * (3 * Dn) + g * 8);
      kf[c][1] = *(const s16x8*)(kbase + (size_t)c * 16 * (3 * Dn) + 32 + g * 8);
    }
    // ---- bias loads, all 16 batch-issued into registers ----
    float bb[4][4];
#pragma unroll
    for (int c = 0; c < 4; c++)
#pragma unroll
      for (int r = 0; r < 4; r++)
        bb[c][r] = biasrow[(size_t)r * Sn + kc0 + c * 16 + lt] * C2;
    // ---- QK^T ----
    f32x4 s[4] = {};
#pragma unroll
    for (int c = 0; c < 4; c++) {
      s[c] = MFMA(qf0, kf[c][0], s[c]);
      s[c] = MFMA(qf1, kf[c][1], s[c]);
    }
    // ---- V fragment loads issued here; latency hides under softmax ----
    const short* vbase = vt + ((size_t)bh * DKn + lt) * Sn + kc0 + g * 8;
    s16x8 vf[4][2];
#pragma unroll
    for (int dt = 0; dt < 4; dt++) {
      vf[dt][0] = *(const s16x8*)(vbase + (size_t)dt * 16 * Sn);
      vf[dt][1] = *(const s16x8*)(vbase + (size_t)dt * 16 * Sn + 32);
    }
    // ---- softcap softmax (static max 30): p = exp2(C3 / (1 + exp2(s*C1 + bias*C2)))
    bool needmask = (kc0 + 63 > q0);
#pragma unroll
    for (int c = 0; c < 4; c++) {
#pragma unroll
      for (int r = 0; r < 4; r++) {
        float targ = fmaf(s[c][r], C1, bb[c][r]);
        float t = __builtin_amdgcn_exp2f(targ);
        float u = __builtin_amdgcn_rcpf(1.0f + t);
        float p = __builtin_amdgcn_exp2f(C3 * u);
        if (needmask) p = (kc0 + c * 16 + lt <= q0 + g * 4 + r) ? p : 0.0f;
        lsum[r] += p;
        plds[w][g * 4 + r][c * 16 + lt] = f2bf(p);
      }
    }
    // ---- PV ----
    s16x8 pf0 = *(const s16x8*)&plds[w][lt][g * 8];
    s16x8 pf1 = *(const s16x8*)&plds[w][lt][32 + g * 8];
#pragma unroll
    for (int dt = 0; dt < 4; dt++) {
      oacc[dt] = MFMA(pf0, vf[dt][0], oacc[dt]);
      oacc[dt] = MFMA(pf1, vf[dt][1], oacc[dt]);
    }
  }
  // per-wave row sums (reduce across the 16 lanes of each row group)
#pragma unroll
  for (int r = 0; r < 4; r++) {
    float l = lsum[r];
    l += __shfl_xor(l, 1);
    l += __shfl_xor(l, 2);
    l += __shfl_xor(l, 4);
    l += __shfl_xor(l, 8);
    lsum[r] = l;
  }
#pragma unroll
  for (int dt = 0; dt < 4; dt++)
#pragma unroll
    for (int r = 0; r < 4; r++) obuf[w][g * 4 + r][dt * 16 + lt] = oacc[dt][r];
  if (lt == 0) {
#pragma unroll
    for (int r = 0; r < 4; r++) lsumbuf[w][g * 4 + r] = lsum[r];
  }
  __syncthreads();
  // combine: thread t handles q-row (t>>4), 4 dk cols
  int q = tid >> 4, dk0 = (tid & 15) * 4;
  f32x4 a0 = *(const f32x4*)&obuf[0][q][dk0];
  f32x4 a1 = *(const f32x4*)&obuf[1][q][dk0];
  f32x4 a2 = *(const f32x4*)&obuf[2][q][dk0];
  f32x4 a3 = *(const f32x4*)&obuf[3][q][dk0];
  float l = lsumbuf[0][q] + lsumbuf[1][q] + lsumbuf[2][q] + lsumbuf[3][q];
  float inv = __builtin_amdgcn_rcpf(l);
  f32x4 acc = (a0 + a1) + (a2 + a3);
  s16x4 outv;
  outv[0] = f2bf(acc[0] * inv);
  outv[1] = f2bf(acc[1] * inv);
  outv[2] = f2bf(acc[2] * inv);
  outv[3] = f2bf(acc[3] * inv);
  *(s16x4*)&o[(size_t)(b * Sn + q0 + q) * Dn + h * DKn + dk0] = outv;
}

// ---------------- launch ----------------
extern "C" void kernel_launch(void* const* d_in, const int* in_sizes, int n_in,
                              void* d_out, int out_size, void* d_ws, size_t ws_size,
                              hipStream_t stream) {
  const float* x = (const float*)d_in[0];
  const float* bias = (const float*)d_in[1];
  // d_in[2] = attn_mask (exact causal tril) -> applied analytically
  const float* Wq = (const float*)d_in[3];
  const float* Wk = (const float*)d_in[4];
  const float* Wv = (const float*)d_in[5];
  const float* Wo = (const float*)d_in[6];
  const float* W1 = (const float*)d_in[7];
  const float* W2 = (const float*)d_in[8];
  const float* g1 = (const float*)d_in[9];
  const float* b1 = (const float*)d_in[10];
  const float* g2 = (const float*)d_in[11];
  const float* b2 = (const float*)d_in[12];
  float* out = (float*)d_out;
  char* ws = (char*)d_ws;

  short* wqkv_t = (short*)(ws + 0);          // 2304x768 bf16
  short* wo_t = (short*)(ws + 3538944);      // 768x768
  short* w1_t = (short*)(ws + 4718592);      // 3072x768
  short* w2_t = (short*)(ws + 9437184);      // 768x3072
  short* hb = (short*)(ws + 14155776);       // 4096x768 bf16 (reused as h2b)
  float* hf = (float*)(ws + 20447232);       // 4096x768 f32  (reused as h2f)
  short* qkv = (short*)(ws + 33030144);      // 4096x2304 bf16 (region reused by a1 4096x3072)
  short* a1 = qkv;
  short* vt = (short*)(ws + 58195968);       // 24x64x2048 bf16 (region reused by x1 f32)
  float* x1 = (float*)(ws + 58195968);
  short* o_ = (short*)(ws + 70778880);       // 4096x768 bf16
  short* h2b = hb;
  float* h2f = hf;

  dim3 tb(32, 8);
  wtrans<<<dim3(24, 24), tb, 0, stream>>>(Wq, wqkv_t, Dn, Dn);
  wtrans<<<dim3(24, 24), tb, 0, stream>>>(Wk, wqkv_t + (size_t)Dn * Dn, Dn, Dn);
  wtrans<<<dim3(24, 24), tb, 0, stream>>>(Wv, wqkv_t + (size_t)2 * Dn * Dn, Dn, Dn);
  wtrans<<<dim3(24, 24), tb, 0, stream>>>(Wo, wo_t, Dn, Dn);
  wtrans<<<dim3(96, 24), tb, 0, stream>>>(W1, w1_t, Dn, DFn);
  wtrans<<<dim3(24, 96), tb, 0, stream>>>(W2, w2_t, DFn, Dn);

  ln_kernel<<<Mrows, 256, 0, stream>>>(x, g1, b1, hb, hf);

  gemm_bt<0><<<dim3(32, 18), 256, 0, stream>>>(hb, wqkv_t, qkv, nullptr, nullptr,
                                               Mrows, 3 * Dn, Dn);
  vtrans<<<dim3(64, 2, Bn * Hn), tb, 0, stream>>>(qkv, vt);
  attn_kernel<<<dim3(24, 128), 256, 0, stream>>>(qkv, vt, bias, o_);

  gemm_bt<2><<<dim3(32, 6), 256, 0, stream>>>(o_, wo_t, nullptr, hf, x1,
                                              Mrows, Dn, Dn);
  ln_kernel<<<Mrows, 256, 0, stream>>>(x1, g2, b2, h2b, h2f);
  gemm_bt<1><<<dim3(32, 24), 256, 0, stream>>>(h2b, w1_t, a1, nullptr, nullptr,
                                               Mrows, DFn, Dn);
  gemm_bt<2><<<dim3(32, 6), 256, 0, stream>>>(a1, w2_t, nullptr, h2f, out,
                                              Mrows, Dn, DFn);
}

// Round 4
// 335.106 us; speedup vs baseline: 1.4939x; 1.2499x over previous
//
#include <hip/hip_runtime.h>
#include <hip/hip_bf16.h>
#include <cstdint>

// ---------------- constants ----------------
#define Bn 2
#define Sn 2048
#define Dn 768
#define Hn 12
#define DKn 64
#define DFn 3072
#define Mrows 4096   // B*S

typedef float f32x4 __attribute__((ext_vector_type(4)));
typedef __bf16 bf16x8 __attribute__((ext_vector_type(8)));
typedef short s16x8 __attribute__((ext_vector_type(8)));
typedef short s16x4 __attribute__((ext_vector_type(4)));

__device__ __forceinline__ f32x4 MFMA(s16x8 a, s16x8 b, f32x4 c) {
  return __builtin_amdgcn_mfma_f32_16x16x32_bf16(
      __builtin_bit_cast(bf16x8, a), __builtin_bit_cast(bf16x8, b), c, 0, 0, 0);
}

__device__ __forceinline__ void g2lds16(const void* g, void* l) {
  __builtin_amdgcn_global_load_lds(
      (__attribute__((address_space(1))) void*)(g),
      (__attribute__((address_space(3))) void*)(l), 16, 0, 0);
}

__device__ __forceinline__ short f2bf(float f) {
  unsigned u = __builtin_bit_cast(unsigned, f);
  unsigned r = (u + 0x7fffu + ((u >> 16) & 1u)) >> 16;
  return (short)r;
}

// ---------------- weight transpose: in (R,C) f32 -> out (C,R) bf16 ----------------
__global__ void wtrans(const float* __restrict__ in, short* __restrict__ out, int R, int C) {
  __shared__ float t[32][33];
  int c0 = blockIdx.x * 32, r0 = blockIdx.y * 32;
  int tx = threadIdx.x, ty = threadIdx.y;  // 32 x 8
#pragma unroll
  for (int i = 0; i < 4; i++) t[ty + i * 8][tx] = in[(size_t)(r0 + ty + i * 8) * C + c0 + tx];
  __syncthreads();
#pragma unroll
  for (int i = 0; i < 4; i++) out[(size_t)(c0 + ty + i * 8) * R + r0 + tx] = f2bf(t[tx][ty + i * 8]);
}

// ---------------- layernorm: x f32 (row of 768) -> h bf16 + h f32 ----------------
__global__ __launch_bounds__(256) void ln_kernel(const float* __restrict__ x,
                                                 const float* __restrict__ g,
                                                 const float* __restrict__ b,
                                                 short* __restrict__ hb,
                                                 float* __restrict__ hf) {
  int row = blockIdx.x;
  const float* xr = x + (size_t)row * Dn;
  int tid = threadIdx.x;
  float v[3];
  float s = 0.f, ss = 0.f;
#pragma unroll
  for (int i = 0; i < 3; i++) {
    v[i] = xr[tid + i * 256];
    s += v[i];
    ss += v[i] * v[i];
  }
#pragma unroll
  for (int m = 1; m < 64; m <<= 1) {
    s += __shfl_xor(s, m);
    ss += __shfl_xor(ss, m);
  }
  __shared__ float red[8];
  int w = tid >> 6, lane = tid & 63;
  if (lane == 0) { red[w] = s; red[4 + w] = ss; }
  __syncthreads();
  s = red[0] + red[1] + red[2] + red[3];
  ss = red[4] + red[5] + red[6] + red[7];
  float mean = s * (1.0f / Dn);
  float var = ss * (1.0f / Dn) - mean * mean;
  float rs = rsqrtf(var + 1e-5f);
#pragma unroll
  for (int i = 0; i < 3; i++) {
    int c = tid + i * 256;
    float h = (v[i] - mean) * rs * g[c] + b[c];
    hb[(size_t)row * Dn + c] = f2bf(h);
    hf[(size_t)row * Dn + c] = h;
  }
}

// ---------------- generic 128x128 bf16 GEMM, C = A @ Bt^T ----------------
// EPI 0: C bf16   EPI 1: gelu -> C bf16   EPI 2: Cf = acc + addm (f32)
template <int EPI>
__global__ __launch_bounds__(256) void gemm_bt(const short* __restrict__ A,
                                               const short* __restrict__ Bt,
                                               short* __restrict__ Cb,
                                               const float* __restrict__ addm,
                                               float* __restrict__ Cf,
                                               int M, int N, int K) {
  __shared__ __align__(16) short As[4096];
  __shared__ __align__(16) short Bs[4096];
  int tid = threadIdx.x;
  int lane = tid & 63, w = tid >> 6, g = lane >> 4, lt = lane & 15;
  int wr = w >> 1, wc = w & 1;
  int m0 = blockIdx.x * 128, n0 = blockIdx.y * 128;
  int sr = tid >> 2, su = (tid & 3) * 8;
  const short* Ag = A + (size_t)(m0 + sr) * K + su;
  const short* Bg = Bt + (size_t)(n0 + sr) * K + su;
  f32x4 acc[4][4] = {};
  for (int k0 = 0; k0 < K; k0 += 32) {
    g2lds16(Ag + k0, &As[tid * 8]);
    g2lds16(Ag + k0 + (size_t)64 * K, &As[2048 + tid * 8]);
    g2lds16(Bg + k0, &Bs[tid * 8]);
    g2lds16(Bg + k0 + (size_t)64 * K, &Bs[2048 + tid * 8]);
    __syncthreads();
    s16x8 af[4], bfr[4];
#pragma unroll
    for (int i = 0; i < 4; i++) {
      af[i] = *(const s16x8*)&As[(wr * 64 + i * 16 + lt) * 32 + g * 8];
      bfr[i] = *(const s16x8*)&Bs[(wc * 64 + i * 16 + lt) * 32 + g * 8];
    }
#pragma unroll
    for (int mi = 0; mi < 4; mi++)
#pragma unroll
      for (int ni = 0; ni < 4; ni++) acc[mi][ni] = MFMA(af[mi], bfr[ni], acc[mi][ni]);
    __syncthreads();
  }
#pragma unroll
  for (int mi = 0; mi < 4; mi++) {
    int m = m0 + wr * 64 + mi * 16 + g * 4;
#pragma unroll
    for (int ni = 0; ni < 4; ni++) {
      int n = n0 + wc * 64 + ni * 16 + lt;
#pragma unroll
      for (int r = 0; r < 4; r++) {
        float v = acc[mi][ni][r];
        size_t idx = (size_t)(m + r) * N + n;
        if constexpr (EPI == 0) {
          Cb[idx] = f2bf(v);
        } else if constexpr (EPI == 1) {
          float ge = 0.5f * v * (1.0f + erff(v * 0.70710678f));
          Cb[idx] = f2bf(ge);
        } else {
          Cf[idx] = v + addm[idx];
        }
      }
    }
  }
}

// ---------------- 64x64-tile bf16 GEMM for skinny-N, double-buffered, swizzled ----
// C = A @ Bt^T.  EPI 2: Cf = acc + addm (f32).  grid (M/64, N/64), 256 thr.
template <int EPI>
__global__ __launch_bounds__(256, 4) void gemm64(const short* __restrict__ A,
                                                 const short* __restrict__ Bt,
                                                 short* __restrict__ Cb,
                                                 const float* __restrict__ addm,
                                                 float* __restrict__ Cf,
                                                 int M, int N, int K) {
  __shared__ __align__(16) short As[2][4096];
  __shared__ __align__(16) short Bs[2][4096];
  int tid = threadIdx.x, lane = tid & 63, w = tid >> 6, g = lane >> 4, lt = lane & 15;
  int wr = w >> 1, wc = w & 1;
  int m0 = blockIdx.x * 64, n0 = blockIdx.y * 64;
  // staging: chunk i = hh*256+tid -> tile row i>>3, swizzled src chunk (i&7)^(row&7)
  int r0 = tid >> 3, cc = (tid & 7) ^ (r0 & 7);  // hh=1 row = r0+32 -> same swizzle
  const short* asrc0 = A + (size_t)(m0 + r0) * K + cc * 8;
  const short* asrc1 = A + (size_t)(m0 + r0 + 32) * K + cc * 8;
  const short* bsrc0 = Bt + (size_t)(n0 + r0) * K + cc * 8;
  const short* bsrc1 = Bt + (size_t)(n0 + r0 + 32) * K + cc * 8;
  int sw = lt & 7;
  int ch0 = (g ^ sw) * 8, ch1 = ((4 + g) ^ sw) * 8;  // swizzled k-chunk offsets (shorts)
  f32x4 acc[2][2] = {};
  g2lds16(asrc0, &As[0][tid * 8]);
  g2lds16(asrc1, &As[0][2048 + tid * 8]);
  g2lds16(bsrc0, &Bs[0][tid * 8]);
  g2lds16(bsrc1, &Bs[0][2048 + tid * 8]);
  __syncthreads();
  int nsteps = K >> 6;
  for (int t = 0; t < nsteps; t++) {
    int cur = t & 1;
    if (t + 1 < nsteps) {
      int k0 = (t + 1) << 6;
      g2lds16(asrc0 + k0, &As[cur ^ 1][tid * 8]);
      g2lds16(asrc1 + k0, &As[cur ^ 1][2048 + tid * 8]);
      g2lds16(bsrc0 + k0, &Bs[cur ^ 1][tid * 8]);
      g2lds16(bsrc1 + k0, &Bs[cur ^ 1][2048 + tid * 8]);
    }
    s16x8 af[2][2], bf[2][2];
#pragma unroll
    for (int mi = 0; mi < 2; mi++) {
      af[mi][0] = *(const s16x8*)&As[cur][(wr * 32 + mi * 16 + lt) * 64 + ch0];
      af[mi][1] = *(const s16x8*)&As[cur][(wr * 32 + mi * 16 + lt) * 64 + ch1];
    }
#pragma unroll
    for (int ni = 0; ni < 2; ni++) {
      bf[ni][0] = *(const s16x8*)&Bs[cur][(wc * 32 + ni * 16 + lt) * 64 + ch0];
      bf[ni][1] = *(const s16x8*)&Bs[cur][(wc * 32 + ni * 16 + lt) * 64 + ch1];
    }
#pragma unroll
    for (int mi = 0; mi < 2; mi++)
#pragma unroll
      for (int ni = 0; ni < 2; ni++) {
        acc[mi][ni] = MFMA(af[mi][0], bf[ni][0], acc[mi][ni]);
        acc[mi][ni] = MFMA(af[mi][1], bf[ni][1], acc[mi][ni]);
      }
    __syncthreads();
  }
#pragma unroll
  for (int mi = 0; mi < 2; mi++) {
    int m = m0 + wr * 32 + mi * 16 + g * 4;
#pragma unroll
    for (int ni = 0; ni < 2; ni++) {
      int n = n0 + wc * 32 + ni * 16 + lt;
#pragma unroll
      for (int r = 0; r < 4; r++) {
        float v = acc[mi][ni][r];
        size_t idx = (size_t)(m + r) * N + n;
        if constexpr (EPI == 0) {
          Cb[idx] = f2bf(v);
        } else if constexpr (EPI == 1) {
          float ge = 0.5f * v * (1.0f + erff(v * 0.70710678f));
          Cb[idx] = f2bf(ge);
        } else {
          Cf[idx] = v + addm[idx];
        }
      }
    }
  }
}

// ---------------- V transpose: qkv v-cols -> vt (B,H,DK,S) bf16 ----------------
__global__ void vtrans(const short* __restrict__ qkv, short* __restrict__ vt) {
  __shared__ short t[32][33];
  int bh = blockIdx.z;
  int b = bh / Hn, h = bh % Hn;
  int s0 = blockIdx.x * 32, d0 = blockIdx.y * 32;
  int tx = threadIdx.x, ty = threadIdx.y;
#pragma unroll
  for (int i = 0; i < 4; i++)
    t[ty + i * 8][tx] =
        qkv[(size_t)(b * Sn + s0 + ty + i * 8) * (3 * Dn) + 2 * Dn + h * DKn + d0 + tx];
  __syncthreads();
#pragma unroll
  for (int i = 0; i < 4; i++)
    vt[(size_t)(bh * DKn + d0 + ty + i * 8) * Sn + s0 + tx] = t[tx][ty + i * 8];
}

// ---------------- fused attention: 64-row Q-tile, LDS-staged K/V, double-buffered --
// Block: 4 waves, wave w owns q-rows [qt*64+w*16, +16) over the whole causal range.
// K tile [64 kc][64 dk] and V^T tile [64 dk][64 kc] staged to LDS via global_load_lds
// with XOR-swizzled global source (linear LDS dest), read back with swizzled ds_read.
// Static-max softcap softmax (scores <= 30) -> no online rescale, no cross-wave combine.
__global__ __launch_bounds__(256, 3) void attn_kernel(const short* __restrict__ qkv,
                                                      const short* __restrict__ vt,
                                                      const float* __restrict__ bias,
                                                      short* __restrict__ o) {
  __shared__ __align__(16) short Ks[2][4096];
  __shared__ __align__(16) short Vs[2][4096];
  __shared__ __align__(16) short plds[4][16][72];
  int bh = blockIdx.x;
  int by = blockIdx.y;
  int qt = (by & 1) ? (31 - (by >> 1)) : (by >> 1);  // snake: mix long/short blocks
  int b = bh / Hn, h = bh - b * Hn;
  int tid = threadIdx.x, w = tid >> 6, lane = tid & 63, g = lane >> 4, lt = lane & 15;
  int q0 = qt * 64 + w * 16;
  const short* qbase = qkv + (size_t)(b * Sn + q0 + lt) * (3 * Dn) + h * DKn;
  s16x8 qf0 = *(const s16x8*)(qbase + g * 8);
  s16x8 qf1 = *(const s16x8*)(qbase + 32 + g * 8);
  // staging source pointers: chunk i = hh*256+tid, tile row i>>3, chunk (i&7)^(row&7)
  int sr0 = tid >> 3, scc = (tid & 7) ^ (sr0 & 7);  // hh=1 row = sr0+32 -> same scc
  const short* kseg = qkv + (size_t)b * Sn * (3 * Dn) + Dn + h * DKn;
  const short* ksrc0 = kseg + (size_t)sr0 * (3 * Dn) + scc * 8;
  const short* ksrc1 = kseg + (size_t)(sr0 + 32) * (3 * Dn) + scc * 8;
  const short* vseg = vt + (size_t)bh * DKn * Sn;
  const short* vsrc0 = vseg + (size_t)sr0 * Sn + scc * 8;
  const short* vsrc1 = vseg + (size_t)(sr0 + 32) * Sn + scc * 8;
  int sw = lt & 7;
  int ch0 = (g ^ sw) * 8, ch1 = ((4 + g) ^ sw) * 8;
  const float* biasrow = bias + ((size_t)b * Sn + q0 + g * 4) * Sn;
  const float C1 = 0.0120224586f;   // 0.125/15*log2(e)
  const float C2 = 0.0961796722f;   // (1/15)*log2(e)
  const float C3 = -86.5617013f;    // -60*log2(e)
  f32x4 oacc[4] = {};
  float lsum[4] = {0.f, 0.f, 0.f, 0.f};
  // prologue: stage tile 0
  g2lds16(ksrc0, &Ks[0][tid * 8]);
  g2lds16(ksrc1, &Ks[0][2048 + tid * 8]);
  g2lds16(vsrc0, &Vs[0][tid * 8]);
  g2lds16(vsrc1, &Vs[0][2048 + tid * 8]);
  __syncthreads();
  for (int t = 0; t <= qt; t++) {
    int cur = t & 1;
    int kc0 = t * 64;
    if (t < qt) {  // prefetch next k-tile into other buffer
      size_t koff = (size_t)(kc0 + 64) * (3 * Dn);
      g2lds16(ksrc0 + koff, &Ks[cur ^ 1][tid * 8]);
      g2lds16(ksrc1 + koff, &Ks[cur ^ 1][2048 + tid * 8]);
      g2lds16(vsrc0 + kc0 + 64, &Vs[cur ^ 1][tid * 8]);
      g2lds16(vsrc1 + kc0 + 64, &Vs[cur ^ 1][2048 + tid * 8]);
    }
    // bias loads (global, issued early; latency hides under ds_reads + QK)
    float bb[4][4];
#pragma unroll
    for (int c = 0; c < 4; c++)
#pragma unroll
      for (int r = 0; r < 4; r++)
        bb[c][r] = biasrow[(size_t)r * Sn + kc0 + c * 16 + lt] * C2;
    // K fragments from LDS (swizzled)
    s16x8 kf[4][2];
#pragma unroll
    for (int c = 0; c < 4; c++) {
      kf[c][0] = *(const s16x8*)&Ks[cur][(c * 16 + lt) * 64 + ch0];
      kf[c][1] = *(const s16x8*)&Ks[cur][(c * 16 + lt) * 64 + ch1];
    }
    f32x4 s[4] = {};
#pragma unroll
    for (int c = 0; c < 4; c++) {
      s[c] = MFMA(qf0, kf[c][0], s[c]);
      s[c] = MFMA(qf1, kf[c][1], s[c]);
    }
    // V fragments from LDS
    s16x8 vf[4][2];
#pragma unroll
    for (int dt = 0; dt < 4; dt++) {
      vf[dt][0] = *(const s16x8*)&Vs[cur][(dt * 16 + lt) * 64 + ch0];
      vf[dt][1] = *(const s16x8*)&Vs[cur][(dt * 16 + lt) * 64 + ch1];
    }
    // softcap softmax, static max 30: p = exp2(C3 / (1 + exp2(s*C1 + bias*C2)))
    bool needmask = (t == qt);
#pragma unroll
    for (int c = 0; c < 4; c++) {
#pragma unroll
      for (int r = 0; r < 4; r++) {
        float targ = fmaf(s[c][r], C1, bb[c][r]);
        float e = __builtin_amdgcn_exp2f(targ);
        float u = __builtin_amdgcn_rcpf(1.0f + e);
        float p = __builtin_amdgcn_exp2f(C3 * u);
        if (needmask) p = (kc0 + c * 16 + lt <= q0 + g * 4 + r) ? p : 0.0f;
        lsum[r] += p;
        plds[w][g * 4 + r][c * 16 + lt] = f2bf(p);
      }
    }
    // P round-trip (C-layout -> A-layout) and PV
    s16x8 pf0 = *(const s16x8*)&plds[w][lt][g * 8];
    s16x8 pf1 = *(const s16x8*)&plds[w][lt][32 + g * 8];
#pragma unroll
    for (int dt = 0; dt < 4; dt++) {
      oacc[dt] = MFMA(pf0, vf[dt][0], oacc[dt]);
      oacc[dt] = MFMA(pf1, vf[dt][1], oacc[dt]);
    }
    __syncthreads();
  }
  // normalize and store (wave owns its rows completely)
  float inv[4];
#pragma unroll
  for (int r = 0; r < 4; r++) {
    float l = lsum[r];
    l += __shfl_xor(l, 1);
    l += __shfl_xor(l, 2);
    l += __shfl_xor(l, 4);
    l += __shfl_xor(l, 8);
    inv[r] = __builtin_amdgcn_rcpf(l);
  }
  short* obase = o + (size_t)(b * Sn + q0 + g * 4) * Dn + h * DKn + lt;
#pragma unroll
  for (int dt = 0; dt < 4; dt++)
#pragma unroll
    for (int r = 0; r < 4; r++) obase[(size_t)r * Dn + dt * 16] = f2bf(oacc[dt][r] * inv[r]);
}

// ---------------- launch ----------------
extern "C" void kernel_launch(void* const* d_in, const int* in_sizes, int n_in,
                              void* d_out, int out_size, void* d_ws, size_t ws_size,
                              hipStream_t stream) {
  const float* x = (const float*)d_in[0];
  const float* bias = (const float*)d_in[1];
  // d_in[2] = attn_mask (exact causal tril) -> applied analytically
  const float* Wq = (const float*)d_in[3];
  const float* Wk = (const float*)d_in[4];
  const float* Wv = (const float*)d_in[5];
  const float* Wo = (const float*)d_in[6];
  const float* W1 = (const float*)d_in[7];
  const float* W2 = (const float*)d_in[8];
  const float* g1 = (const float*)d_in[9];
  const float* b1 = (const float*)d_in[10];
  const float* g2 = (const float*)d_in[11];
  const float* b2 = (const float*)d_in[12];
  float* out = (float*)d_out;
  char* ws = (char*)d_ws;

  short* wqkv_t = (short*)(ws + 0);          // 2304x768 bf16
  short* wo_t = (short*)(ws + 3538944);      // 768x768
  short* w1_t = (short*)(ws + 4718592);      // 3072x768
  short* w2_t = (short*)(ws + 9437184);      // 768x3072
  short* hb = (short*)(ws + 14155776);       // 4096x768 bf16 (reused as h2b)
  float* hf = (float*)(ws + 20447232);       // 4096x768 f32  (reused as h2f)
  short* qkv = (short*)(ws + 33030144);      // 4096x2304 bf16 (region reused by a1 4096x3072)
  short* a1 = qkv;
  short* vt = (short*)(ws + 58195968);       // 24x64x2048 bf16 (region reused by x1 f32)
  float* x1 = (float*)(ws + 58195968);
  short* o_ = (short*)(ws + 70778880);       // 4096x768 bf16
  short* h2b = hb;
  float* h2f = hf;

  dim3 tb(32, 8);
  wtrans<<<dim3(24, 24), tb, 0, stream>>>(Wq, wqkv_t, Dn, Dn);
  wtrans<<<dim3(24, 24), tb, 0, stream>>>(Wk, wqkv_t + (size_t)Dn * Dn, Dn, Dn);
  wtrans<<<dim3(24, 24), tb, 0, stream>>>(Wv, wqkv_t + (size_t)2 * Dn * Dn, Dn, Dn);
  wtrans<<<dim3(24, 24), tb, 0, stream>>>(Wo, wo_t, Dn, Dn);
  wtrans<<<dim3(96, 24), tb, 0, stream>>>(W1, w1_t, Dn, DFn);
  wtrans<<<dim3(24, 96), tb, 0, stream>>>(W2, w2_t, DFn, Dn);

  ln_kernel<<<Mrows, 256, 0, stream>>>(x, g1, b1, hb, hf);

  gemm_bt<0><<<dim3(32, 18), 256, 0, stream>>>(hb, wqkv_t, qkv, nullptr, nullptr,
                                               Mrows, 3 * Dn, Dn);
  vtrans<<<dim3(64, 2, Bn * Hn), tb, 0, stream>>>(qkv, vt);
  attn_kernel<<<dim3(24, 32), 256, 0, stream>>>(qkv, vt, bias, o_);

  gemm64<2><<<dim3(64, 12), 256, 0, stream>>>(o_, wo_t, nullptr, hf, x1,
                                              Mrows, Dn, Dn);
  ln_kernel<<<Mrows, 256, 0, stream>>>(x1, g2, b2, h2b, h2f);
  gemm_bt<1><<<dim3(32, 24), 256, 0, stream>>>(h2b, w1_t, a1, nullptr, nullptr,
                                               Mrows, DFn, Dn);
  gemm64<2><<<dim3(64, 12), 256, 0, stream>>>(a1, w2_t, nullptr, h2f, out,
                                              Mrows, Dn, DFn);
}